// Round 6
// baseline (189.950 us; speedup 1.0000x reference)
//
#include <hip/hip_runtime.h>

// Model_47510928228872: 2-layer bidirectional LSTM (H=3) + linear + sigmoid.
// B=8192, T=512, fp32.
//
// Round 6: dependency-latency-bound at 1 wave/SIMD -> split the 4 gates of
// each cell across two quads (q=0: packed (i,f); q=1: packed (g,o)), exchange
// via row_shl:4/row_shr:4 DPP, both quads redundantly update c,h.
//  K1 (l0-bwd): 8 lanes/batch  -> 1024 waves (1/SIMD, was 0.5/SIMD).
//  K2 (l0f+l1f): 16 lanes/batch -> 2048 waves (2/SIMD, was 1/SIMD).
// Uniform activation: sigma/tanh both = a*rcp(1+exp2(s*p))+d with per-lane
// (s,a,d). y0b layout [B][64][3 j][8 s], slot t+1 holds h_bwd(t).

#define B_ 8192
#define T_ 512
#define LOG2E 1.4426950408889634f

typedef float v2f __attribute__((ext_vector_type(2)));

__device__ __forceinline__ float rcp_(float x)  { return __builtin_amdgcn_rcpf(x); }
__device__ __forceinline__ float exp2_(float x) { return __builtin_amdgcn_exp2f(x); }
__device__ __forceinline__ float sigm_(float x) {
  return rcp_(1.0f + exp2_(-LOG2E * x));
}
__device__ __forceinline__ float tanh_(float x) {
  return 1.0f - 2.0f * rcp_(1.0f + exp2_(2.0f * LOG2E * x));
}
__device__ __forceinline__ v2f sp(float s) { return (v2f){s, s}; }
__device__ __forceinline__ v2f pkfma(v2f a, float b, v2f c) {
  return __builtin_elementwise_fma(a, sp(b), c);
}

template <int CTRL>
__device__ __forceinline__ float dppf(float v) {
  int s = __float_as_int(v);
  return __int_as_float(__builtin_amdgcn_update_dpp(s, s, CTRL, 0xF, 0xF, false));
}
#define QB0 0x00   // quad_perm broadcast lane0 of quad
#define QB1 0x55
#define QB2 0xAA
#define SHL4 0x104 // row_shl:4 (lane i <- i+4)
#define SHR4 0x114 // row_shr:4 (lane i <- i-4)
#define SHR8 0x118 // row_shr:8 (lane i <- i-8)

// ---------------- Kernel 1: layer-0 backward (8 lanes/batch) ----------------
__global__ __launch_bounds__(256, 2) void lstm_l0_bwd(
    const float* __restrict__ x,      // [B][T][3]
    const float* __restrict__ Wih, const float* __restrict__ Whh,
    const float* __restrict__ bih, const float* __restrict__ bhh,
    float* __restrict__ y0b)          // [B][64][3][8], slot t+1 holds h_bwd(t)
{
  int tid = blockIdx.x * 256 + threadIdx.x;
  int b = tid >> 3, lane = tid & 7;
  bool qgo = (lane & 4) != 0;         // quad role: false=(i,f), true=(g,o)
  int j = lane & 3; int jj = (j < 3) ? j : 0;
  const int ra = (qgo ? 6 : 0) + jj, rb = ra + 3;

  v2f w0 = {Wih[ra*3+0], Wih[rb*3+0]}, w1 = {Wih[ra*3+1], Wih[rb*3+1]},
      w2 = {Wih[ra*3+2], Wih[rb*3+2]};
  v2f u0 = {Whh[ra*3+0], Whh[rb*3+0]}, u1 = {Whh[ra*3+1], Whh[rb*3+1]},
      u2 = {Whh[ra*3+2], Whh[rb*3+2]};
  v2f b2 = {bih[ra]+bhh[ra], bih[rb]+bhh[rb]};
  v2f sv = qgo ? (v2f){-2.f*LOG2E, -LOG2E} : (v2f){-LOG2E, -LOG2E};
  v2f av = qgo ? (v2f){2.f, 1.f}  : (v2f){1.f, 1.f};
  v2f dv = qgo ? (v2f){-1.f, 0.f} : (v2f){0.f, 0.f};

  float h = 0.f, c = 0.f, ha0 = 0.f, ha1 = 0.f, ha2 = 0.f;
  const float4* xq = (const float4*)(x + (size_t)b * (T_ * 3));
  float* ywb = y0b + (size_t)b * (T_ * 3) + jj * 8;

  float hs0 = 0.f, hs1 = 0.f, hs2 = 0.f, hs3 = 0.f,
        hs4 = 0.f, hs5 = 0.f, hs6 = 0.f, hs7 = 0.f, h511 = 0.f;
  float4 p0, p1, p2, p3, p4, p5, q0, q1, q2, q3, q4, q5;

#define LD1(blk, r0_, r1_, r2_, r3_, r4_, r5_) do {                       \
    const float4* _p = xq + (blk) * 6;                                    \
    r0_ = _p[0]; r1_ = _p[1]; r2_ = _p[2];                                \
    r3_ = _p[3]; r4_ = _p[4]; r5_ = _p[5];                                \
    __builtin_amdgcn_sched_barrier(0); } while (0)

#define STEP1(x0, x1, x2, HOUT) do {                                      \
    v2f pv = pkfma(w0, (x0), b2); pv = pkfma(w1, (x1), pv);               \
    pv = pkfma(w2, (x2), pv);                                             \
    v2f uv = u0 * sp(ha0); uv = pkfma(u1, ha1, uv);                       \
    uv = pkfma(u2, ha2, uv);                                              \
    pv = pv + uv;                                                         \
    v2f e = pv * sv;                                                      \
    float r0v = rcp_(1.f + exp2_(e.x));                                   \
    float r1v = rcp_(1.f + exp2_(e.y));                                   \
    float axv = __builtin_fmaf(av.x, r0v, dv.x);                          \
    float ayv = __builtin_fmaf(av.y, r1v, dv.y);                          \
    float slx = dppf<SHL4>(axv), sly = dppf<SHL4>(ayv);                   \
    float srx = dppf<SHR4>(axv), sry = dppf<SHR4>(ayv);                   \
    float gi = qgo ? srx : axv;                                           \
    float gf = qgo ? sry : ayv;                                           \
    float gG = qgo ? axv : slx;                                           \
    float gO = qgo ? ayv : sly;                                           \
    c = gf * c + gi * gG;                                                 \
    h = gO * tanh_(c);                                                    \
    ha0 = dppf<QB0>(h); ha1 = dppf<QB1>(h); ha2 = dppf<QB2>(h);           \
    HOUT = h; } while (0)

#define FLUSH1(yblk) do {                                                 \
    if (lane < 3) {                                                       \
      float4* _o = (float4*)(ywb + (yblk) * 24);                          \
      _o[0] = make_float4(hs0, hs1, hs2, hs3);                            \
      _o[1] = make_float4(hs4, hs5, hs6, hs7);                            \
    } } while (0)

#define PROC1(blk, r0_, r1_, r2_, r3_, r4_, r5_, FIRST) do {              \
    STEP1(r5_.y, r5_.z, r5_.w, hs0);                                      \
    if (FIRST) h511 = hs0; else FLUSH1((blk) + 1);                        \
    STEP1(r4_.z, r4_.w, r5_.x, hs7);                                      \
    STEP1(r3_.w, r4_.x, r4_.y, hs6);                                      \
    STEP1(r3_.x, r3_.y, r3_.z, hs5);                                      \
    STEP1(r2_.y, r2_.z, r2_.w, hs4);                                      \
    STEP1(r1_.z, r1_.w, r2_.x, hs3);                                      \
    STEP1(r0_.w, r1_.x, r1_.y, hs2);                                      \
    STEP1(r0_.x, r0_.y, r0_.z, hs1); } while (0)

  LD1(63, p0, p1, p2, p3, p4, p5);
  LD1(62, q0, q1, q2, q3, q4, q5);
  PROC1(63, p0, p1, p2, p3, p4, p5, true);
  LD1(61, p0, p1, p2, p3, p4, p5);
  PROC1(62, q0, q1, q2, q3, q4, q5, false);
  LD1(60, q0, q1, q2, q3, q4, q5);
  for (int blk = 61; blk >= 1; blk -= 2) {
    PROC1(blk, p0, p1, p2, p3, p4, p5, false);
    if (blk >= 3) LD1(blk - 2, p0, p1, p2, p3, p4, p5);
    PROC1(blk - 1, q0, q1, q2, q3, q4, q5, false);
    if (blk >= 3) LD1(blk - 3, q0, q1, q2, q3, q4, q5);
  }
  hs0 = h511;
  FLUSH1(0);
#undef LD1
#undef STEP1
#undef FLUSH1
#undef PROC1
}

// ------------- Kernel 2: l0-fwd + l1-fwd fused (16 lanes/batch) -------------
__global__ __launch_bounds__(256, 2) void lstm_fused_fwd(
    const float* __restrict__ x,
    const float* __restrict__ Wih0, const float* __restrict__ Whh0,
    const float* __restrict__ bih0, const float* __restrict__ bhh0,
    const float* __restrict__ Wih1, const float* __restrict__ Whh1,
    const float* __restrict__ bih1, const float* __restrict__ bhh1,
    const float* __restrict__ Wih1r, const float* __restrict__ Whh1r,
    const float* __restrict__ bih1r, const float* __restrict__ bhh1r,
    const float* __restrict__ Wlin, const float* __restrict__ blin,
    const float* __restrict__ y0b,   // [B][64][3][8] shifted
    float* __restrict__ out)         // [B]
{
  int tid = blockIdx.x * 256 + threadIdx.x;
  int b = tid >> 4, lane = tid & 15;
  bool cell1 = lane >= 8;             // lanes 8-15 = layer-1 fwd cell
  bool qgo = (lane & 4) != 0;
  int j = lane & 3; int jj = (j < 3) ? j : 0;
  const int ra = (qgo ? 6 : 0) + jj, rb = ra + 3;

  // 6 input weights + 3 recurrent + bias, packed (row_a, row_b).
  v2f w0, w1, w2, w3, w4, w5, u0, u1, u2, b2;
  if (!cell1) {
    w0 = (v2f){Wih0[ra*3+0], Wih0[rb*3+0]};
    w1 = (v2f){Wih0[ra*3+1], Wih0[rb*3+1]};
    w2 = (v2f){Wih0[ra*3+2], Wih0[rb*3+2]};
    w3 = (v2f){0.f, 0.f}; w4 = (v2f){0.f, 0.f}; w5 = (v2f){0.f, 0.f};
    u0 = (v2f){Whh0[ra*3+0], Whh0[rb*3+0]};
    u1 = (v2f){Whh0[ra*3+1], Whh0[rb*3+1]};
    u2 = (v2f){Whh0[ra*3+2], Whh0[rb*3+2]};
    b2 = (v2f){bih0[ra]+bhh0[ra], bih0[rb]+bhh0[rb]};
  } else {
    w0 = (v2f){Wih1[ra*6+0], Wih1[rb*6+0]};
    w1 = (v2f){Wih1[ra*6+1], Wih1[rb*6+1]};
    w2 = (v2f){Wih1[ra*6+2], Wih1[rb*6+2]};
    w3 = (v2f){Wih1[ra*6+3], Wih1[rb*6+3]};
    w4 = (v2f){Wih1[ra*6+4], Wih1[rb*6+4]};
    w5 = (v2f){Wih1[ra*6+5], Wih1[rb*6+5]};
    u0 = (v2f){Whh1[ra*3+0], Whh1[rb*3+0]};
    u1 = (v2f){Whh1[ra*3+1], Whh1[rb*3+1]};
    u2 = (v2f){Whh1[ra*3+2], Whh1[rb*3+2]};
    b2 = (v2f){bih1[ra]+bhh1[ra], bih1[rb]+bhh1[rb]};
  }
  v2f sv = qgo ? (v2f){-2.f*LOG2E, -LOG2E} : (v2f){-LOG2E, -LOG2E};
  v2f av = qgo ? (v2f){2.f, 1.f}  : (v2f){1.f, 1.f};
  v2f dv = qgo ? (v2f){-1.f, 0.f} : (v2f){0.f, 0.f};

  float h = 0.f, c = 0.f;
  float ha0 = 0.f, ha1 = 0.f, ha2 = 0.f;  // own cell h(t-1)
  float hb0 = 0.f, hb1 = 0.f, hb2 = 0.f;  // l0 cell h(t-1), for cell1 input
  const float4* baseq =
      (const float4*)((cell1 ? y0b : x) + (size_t)b * (T_ * 3));

  // y0b block 0 slot 0 = h_bwd(T-1)[j] at j-plane offsets 0,8,16.
  const float* up = y0b + (size_t)b * (T_ * 3);
  float ub0 = up[0], ub1 = up[8], ub2 = up[16];

  float4 p0, p1, p2, p3, p4, p5, q0, q1, q2, q3, q4, q5;

#define LD2(blk, r0_, r1_, r2_, r3_, r4_, r5_) do {                       \
    const float4* _p = baseq + (blk) * 6;                                 \
    r0_ = _p[0]; r1_ = _p[1]; r2_ = _p[2];                                \
    r3_ = _p[3]; r4_ = _p[4]; r5_ = _p[5];                                \
    __builtin_amdgcn_sched_barrier(0); } while (0)

#define GATES2(m0, m1, m2, n0, n1, n2) /* -> cn, hn */                    \
    float i0 = cell1 ? hb0 : (m0);                                        \
    float i1 = cell1 ? hb1 : (m1);                                        \
    float i2 = cell1 ? hb2 : (m2);                                        \
    v2f pv = pkfma(w0, i0, b2); pv = pkfma(w1, i1, pv);                   \
    pv = pkfma(w2, i2, pv);                                               \
    pv = pkfma(w3, (n0), pv); pv = pkfma(w4, (n1), pv);                   \
    v2f uv = w5 * sp(n2); uv = pkfma(u0, ha0, uv);                        \
    uv = pkfma(u1, ha1, uv); uv = pkfma(u2, ha2, uv);                     \
    pv = pv + uv;                                                         \
    v2f e = pv * sv;                                                      \
    float r0v = rcp_(1.f + exp2_(e.x));                                   \
    float r1v = rcp_(1.f + exp2_(e.y));                                   \
    float axv = __builtin_fmaf(av.x, r0v, dv.x);                          \
    float ayv = __builtin_fmaf(av.y, r1v, dv.y);                          \
    float slx = dppf<SHL4>(axv), sly = dppf<SHL4>(ayv);                   \
    float srx = dppf<SHR4>(axv), sry = dppf<SHR4>(ayv);                   \
    float gi = qgo ? srx : axv;                                           \
    float gf = qgo ? sry : ayv;                                           \
    float gG = qgo ? axv : slx;                                           \
    float gO = qgo ? ayv : sly;                                           \
    float cn = gf * c + gi * gG;                                          \
    float hn = gO * tanh_(cn);

#define BCAST2() do {                                                     \
    ha0 = dppf<QB0>(h); ha1 = dppf<QB1>(h); ha2 = dppf<QB2>(h);           \
    hb0 = dppf<SHR8>(ha0); hb1 = dppf<SHR8>(ha1); hb2 = dppf<SHR8>(ha2);  \
  } while (0)

#define STEP2(m0, m1, m2, n0, n1, n2) do {                                \
    GATES2(m0, m1, m2, n0, n1, n2)                                        \
    c = cn; h = hn;                                                       \
    BCAST2(); } while (0)

#define STEP2V(m0, m1, m2, n0, n1, n2, VALID) do {                        \
    GATES2(m0, m1, m2, n0, n1, n2)                                        \
    c = (VALID) ? cn : c; h = (VALID) ? hn : h;                           \
    BCAST2(); } while (0)

  // cell0 reads its block as [8 s][3 k]; cell1 as [3 j][8 s].
#define PROC2(r0_, r1_, r2_, r3_, r4_, r5_) do {                          \
    STEP2(r0_.x, r0_.y, r0_.z,  r0_.x, r2_.x, r4_.x);                     \
    STEP2(r0_.w, r1_.x, r1_.y,  r0_.y, r2_.y, r4_.y);                     \
    STEP2(r1_.z, r1_.w, r2_.x,  r0_.z, r2_.z, r4_.z);                     \
    STEP2(r2_.y, r2_.z, r2_.w,  r0_.w, r2_.w, r4_.w);                     \
    STEP2(r3_.x, r3_.y, r3_.z,  r1_.x, r3_.x, r5_.x);                     \
    STEP2(r3_.w, r4_.x, r4_.y,  r1_.y, r3_.y, r5_.y);                     \
    STEP2(r4_.z, r4_.w, r5_.x,  r1_.z, r3_.z, r5_.z);                     \
    STEP2(r5_.y, r5_.z, r5_.w,  r1_.w, r3_.w, r5_.w); } while (0)

  LD2(0, p0, p1, p2, p3, p4, p5);
  LD2(1, q0, q1, q2, q3, q4, q5);
  // Block 0 peeled: step tt=0 invalid for cell1 (it lags one step).
  STEP2V(p0.x, p0.y, p0.z,  p0.x, p2.x, p4.x, !cell1);
  STEP2(p0.w, p1.x, p1.y,  p0.y, p2.y, p4.y);
  STEP2(p1.z, p1.w, p2.x,  p0.z, p2.z, p4.z);
  STEP2(p2.y, p2.z, p2.w,  p0.w, p2.w, p4.w);
  STEP2(p3.x, p3.y, p3.z,  p1.x, p3.x, p5.x);
  STEP2(p3.w, p4.x, p4.y,  p1.y, p3.y, p5.y);
  STEP2(p4.z, p4.w, p5.x,  p1.z, p3.z, p5.z);
  STEP2(p5.y, p5.z, p5.w,  p1.w, p3.w, p5.w);
  LD2(2, p0, p1, p2, p3, p4, p5);
  PROC2(q0, q1, q2, q3, q4, q5);
  LD2(3, q0, q1, q2, q3, q4, q5);
  for (int blk = 2; blk < 64; blk += 2) {
    PROC2(p0, p1, p2, p3, p4, p5);
    if (blk + 2 < 64) LD2(blk + 2, p0, p1, p2, p3, p4, p5);
    PROC2(q0, q1, q2, q3, q4, q5);
    if (blk + 3 < 64) LD2(blk + 3, q0, q1, q2, q3, q4, q5);
  }
  // Final step tt=512: cell1 processes t=T-1 (inputs hb + ub); cell0 frozen.
  STEP2V(ub0, ub1, ub2,  ub0, ub1, ub2, cell1);
  // cell1 lanes: h = h1_fwd[j](T-1). ha(cell0)/hb(cell1) = h0_fwd(T-1).

  float e0 = cell1 ? hb0 : ha0;
  float e1 = cell1 ? hb1 : ha1;
  float e2 = cell1 ? hb2 : ha2;

  // Layer-1 backward: one step from zero state (f-gate drops), same gate
  // split machinery, inputs (e0..2, ub0..2), all lanes compute.
  float h1b;
  {
    v2f x0w = {Wih1r[ra*6+0], Wih1r[rb*6+0]};
    v2f x1w = {Wih1r[ra*6+1], Wih1r[rb*6+1]};
    v2f x2w = {Wih1r[ra*6+2], Wih1r[rb*6+2]};
    v2f x3w = {Wih1r[ra*6+3], Wih1r[rb*6+3]};
    v2f x4w = {Wih1r[ra*6+4], Wih1r[rb*6+4]};
    v2f x5w = {Wih1r[ra*6+5], Wih1r[rb*6+5]};
    v2f brv = {bih1r[ra]+bhh1r[ra], bih1r[rb]+bhh1r[rb]};
    v2f pv = pkfma(x0w, e0, brv); pv = pkfma(x1w, e1, pv);
    pv = pkfma(x2w, e2, pv);      pv = pkfma(x3w, ub0, pv);
    pv = pkfma(x4w, ub1, pv);     pv = pkfma(x5w, ub2, pv);
    v2f e = pv * sv;
    float r0v = rcp_(1.f + exp2_(e.x));
    float r1v = rcp_(1.f + exp2_(e.y));
    float axv = __builtin_fmaf(av.x, r0v, dv.x);
    float ayv = __builtin_fmaf(av.y, r1v, dv.y);
    float slx = dppf<SHL4>(axv);
    float sly = dppf<SHL4>(ayv);
    float srx = dppf<SHR4>(axv);
    float gi = qgo ? srx : axv;
    float gG = qgo ? axv : slx;
    float gO = qgo ? ayv : sly;
    float cb = gi * gG;               // c_prev = 0
    h1b = gO * tanh_(cb);
  }

  // out[b] = sigmoid(Wlin . [h1_fwd, h1_bwd] + blin)
  float part = 0.f;
  if (!qgo && j < 3) part = cell1 ? (Wlin[j] * h) : (Wlin[3 + j] * h1b);
  part += __shfl_xor(part, 1, 16);
  part += __shfl_xor(part, 2, 16);
  part += __shfl_xor(part, 4, 16);
  part += __shfl_xor(part, 8, 16);
  if (lane == 0) out[b] = sigm_(part + blin[0]);
#undef LD2
#undef GATES2
#undef BCAST2
#undef STEP2
#undef STEP2V
#undef PROC2
}

extern "C" void kernel_launch(void* const* d_in, const int* in_sizes, int n_in,
                              void* d_out, int out_size, void* d_ws, size_t ws_size,
                              hipStream_t stream) {
  const float* x        = (const float*)d_in[0];
  const float* W_ih_l0  = (const float*)d_in[1];
  const float* W_hh_l0  = (const float*)d_in[2];
  const float* b_ih_l0  = (const float*)d_in[3];
  const float* b_hh_l0  = (const float*)d_in[4];
  const float* W_ih_l0r = (const float*)d_in[5];
  const float* W_hh_l0r = (const float*)d_in[6];
  const float* b_ih_l0r = (const float*)d_in[7];
  const float* b_hh_l0r = (const float*)d_in[8];
  const float* W_ih_l1  = (const float*)d_in[9];
  const float* W_hh_l1  = (const float*)d_in[10];
  const float* b_ih_l1  = (const float*)d_in[11];
  const float* b_hh_l1  = (const float*)d_in[12];
  const float* W_ih_l1r = (const float*)d_in[13];
  const float* W_hh_l1r = (const float*)d_in[14];
  const float* b_ih_l1r = (const float*)d_in[15];
  const float* b_hh_l1r = (const float*)d_in[16];
  const float* W_lin    = (const float*)d_in[17];
  const float* b_lin    = (const float*)d_in[18];

  float* y0b = (float*)d_ws;   // [B][64][3][8] fp32 = 48 MB, shifted layout
  float* out = (float*)d_out;

  // K1: 8 lanes/batch -> 65536 threads = 1024 waves (1 wave/SIMD)
  lstm_l0_bwd<<<(B_ * 8) / 256, 256, 0, stream>>>(
      x, W_ih_l0r, W_hh_l0r, b_ih_l0r, b_hh_l0r, y0b);

  // K2: 16 lanes/batch -> 131072 threads = 2048 waves (2 waves/SIMD)
  lstm_fused_fwd<<<(B_ * 16) / 256, 256, 0, stream>>>(
      x, W_ih_l0, W_hh_l0, b_ih_l0, b_hh_l0,
      W_ih_l1, W_hh_l1, b_ih_l1, b_hh_l1,
      W_ih_l1r, W_hh_l1r, b_ih_l1r, b_hh_l1r,
      W_lin, b_lin, y0b, out);
}

// Round 8
// 142.621 us; speedup vs baseline: 1.3318x; 1.3318x over previous
//
#include <hip/hip_runtime.h>

// Model_47510928228872: 2-layer bidirectional LSTM (H=3) + linear + sigmoid.
// B=8192, T=512, fp32.
//
// Round 8 = round 7 with LEGAL packed math (v_pk_fma_f32 needs 64-bit pair
// operands; splats built by the compiler). Tests: (a) gate weights/biases
// pre-scaled by -log2e (sigma rows) / -2log2e (tanh rows) -> activation is
// pure rcp(1+exp2(p)), no per-step scaling; (b) 3x 3-deep parallel MAC
// chains (shorter h->preact critical path).
//  K1 (l0-bwd): round-6 gate-split, 8 lanes/batch.
//  K2 (l0f+l1f): round-5 fused cell, 8 lanes/batch.

#define B_ 8192
#define T_ 512
#define LOG2E 1.4426950408889634f

typedef float v2f __attribute__((ext_vector_type(2)));

__device__ __forceinline__ float rcp_(float x)  { return __builtin_amdgcn_rcpf(x); }
__device__ __forceinline__ float exp2_(float x) { return __builtin_amdgcn_exp2f(x); }
__device__ __forceinline__ float sigm_(float x) {
  return rcp_(1.0f + exp2_(-LOG2E * x));
}
__device__ __forceinline__ float tanh_(float x) {
  return 1.0f - 2.0f * rcp_(1.0f + exp2_(2.0f * LOG2E * x));
}
// activation on PRESCALED preact: rcp(1+exp2(p))
__device__ __forceinline__ float act_(float p) { return rcp_(1.f + exp2_(p)); }

__device__ __forceinline__ v2f sp(float s) { return (v2f){s, s}; }
__device__ __forceinline__ v2f pkfma(v2f a, float b, v2f c) {
  return __builtin_elementwise_fma(a, sp(b), c);
}

template <int CTRL>
__device__ __forceinline__ float dppf(float v) {
  int s = __float_as_int(v);
  return __int_as_float(__builtin_amdgcn_update_dpp(s, s, CTRL, 0xF, 0xF, false));
}
#define QB0 0x00   // quad_perm broadcast lane0 of quad
#define QB1 0x55
#define QB2 0xAA
#define SHL4 0x104 // row_shl:4 (lane i <- i+4)
#define SHR4 0x114 // row_shr:4 (lane i <- i-4)

// ---------------- Kernel 1: layer-0 backward (8 lanes/batch) ----------------
__global__ __launch_bounds__(256, 1) void lstm_l0_bwd(
    const float* __restrict__ x,      // [B][T][3]
    const float* __restrict__ Wih, const float* __restrict__ Whh,
    const float* __restrict__ bih, const float* __restrict__ bhh,
    float* __restrict__ y0b)          // [B][64][3][8], slot t+1 holds h_bwd(t)
{
  int tid = blockIdx.x * 256 + threadIdx.x;
  int b = tid >> 3, lane = tid & 7;
  bool qgo = (lane & 4) != 0;         // quad role: false=(i,f), true=(g,o)
  int j = lane & 3; int jj = (j < 3) ? j : 0;
  const int ra = (qgo ? 6 : 0) + jj, rb = ra + 3;
  // Prescale: row_a by kx (g-row -2L, i-row -L), row_b by ky (-L).
  const float kx = qgo ? (-2.f * LOG2E) : (-LOG2E);
  const float ky = -LOG2E;

  v2f w0 = {Wih[ra*3+0]*kx, Wih[rb*3+0]*ky},
      w1 = {Wih[ra*3+1]*kx, Wih[rb*3+1]*ky},
      w2 = {Wih[ra*3+2]*kx, Wih[rb*3+2]*ky};
  v2f u0 = {Whh[ra*3+0]*kx, Whh[rb*3+0]*ky},
      u1 = {Whh[ra*3+1]*kx, Whh[rb*3+1]*ky},
      u2 = {Whh[ra*3+2]*kx, Whh[rb*3+2]*ky};
  v2f b2 = {(bih[ra]+bhh[ra])*kx, (bih[rb]+bhh[rb])*ky};
  const float avx = qgo ? 2.f : 1.f;
  const float dvx = qgo ? -1.f : 0.f;

  float h = 0.f, c = 0.f, ha0 = 0.f, ha1 = 0.f, ha2 = 0.f;
  const float4* xq = (const float4*)(x + (size_t)b * (T_ * 3));
  float* ywb = y0b + (size_t)b * (T_ * 3) + jj * 8;

  float hs0 = 0.f, hs1 = 0.f, hs2 = 0.f, hs3 = 0.f,
        hs4 = 0.f, hs5 = 0.f, hs6 = 0.f, hs7 = 0.f, h511 = 0.f;
  float4 p0, p1, p2, p3, p4, p5, q0, q1, q2, q3, q4, q5;

#define LD1(blk, r0_, r1_, r2_, r3_, r4_, r5_) do {                       \
    const float4* _p = xq + (blk) * 6;                                    \
    r0_ = _p[0]; r1_ = _p[1]; r2_ = _p[2];                                \
    r3_ = _p[3]; r4_ = _p[4]; r5_ = _p[5];                                \
    __builtin_amdgcn_sched_barrier(0); } while (0)

#define STEP1(x0, x1, x2, HOUT) do {                                      \
    v2f pv = pkfma(w0, (x0), b2); pv = pkfma(w1, (x1), pv);               \
    pv = pkfma(w2, (x2), pv);                                             \
    v2f uv = u0 * sp(ha0); uv = pkfma(u1, ha1, uv);                       \
    uv = pkfma(u2, ha2, uv);                                              \
    pv = pv + uv;                                                         \
    float r0v = act_(pv.x);                                               \
    float ayv = act_(pv.y);            /* f (q0) or o (q1) */             \
    float axv = __builtin_fmaf(avx, r0v, dvx); /* i (q0) / tanh g (q1) */ \
    float slx = dppf<SHL4>(axv), sly = dppf<SHL4>(ayv);                   \
    float srx = dppf<SHR4>(axv), sry = dppf<SHR4>(ayv);                   \
    float pig = axv * (qgo ? srx : slx);   /* i*g on both quads */        \
    float gf  = qgo ? sry : ayv;                                          \
    float gO  = qgo ? ayv : sly;                                          \
    c = __builtin_fmaf(gf, c, pig);                                       \
    float th = __builtin_fmaf(                                            \
        2.f, rcp_(1.f + exp2_(-2.f * LOG2E * c)), -1.f);                  \
    h = gO * th;                                                          \
    ha0 = dppf<QB0>(h); ha1 = dppf<QB1>(h); ha2 = dppf<QB2>(h);           \
    HOUT = h; } while (0)

#define FLUSH1(yblk) do {                                                 \
    if (lane < 3) {                                                       \
      float4* _o = (float4*)(ywb + (yblk) * 24);                          \
      _o[0] = make_float4(hs0, hs1, hs2, hs3);                            \
      _o[1] = make_float4(hs4, hs5, hs6, hs7);                            \
    } } while (0)

#define PROC1(blk, r0_, r1_, r2_, r3_, r4_, r5_, FIRST) do {              \
    STEP1(r5_.y, r5_.z, r5_.w, hs0);                                      \
    if (FIRST) h511 = hs0; else FLUSH1((blk) + 1);                        \
    STEP1(r4_.z, r4_.w, r5_.x, hs7);                                      \
    STEP1(r3_.w, r4_.x, r4_.y, hs6);                                      \
    STEP1(r3_.x, r3_.y, r3_.z, hs5);                                      \
    STEP1(r2_.y, r2_.z, r2_.w, hs4);                                      \
    STEP1(r1_.z, r1_.w, r2_.x, hs3);                                      \
    STEP1(r0_.w, r1_.x, r1_.y, hs2);                                      \
    STEP1(r0_.x, r0_.y, r0_.z, hs1); } while (0)

  LD1(63, p0, p1, p2, p3, p4, p5);
  LD1(62, q0, q1, q2, q3, q4, q5);
  PROC1(63, p0, p1, p2, p3, p4, p5, true);
  LD1(61, p0, p1, p2, p3, p4, p5);
  PROC1(62, q0, q1, q2, q3, q4, q5, false);
  LD1(60, q0, q1, q2, q3, q4, q5);
  for (int blk = 61; blk >= 1; blk -= 2) {
    PROC1(blk, p0, p1, p2, p3, p4, p5, false);
    if (blk >= 3) LD1(blk - 2, p0, p1, p2, p3, p4, p5);
    PROC1(blk - 1, q0, q1, q2, q3, q4, q5, false);
    if (blk >= 3) LD1(blk - 3, q0, q1, q2, q3, q4, q5);
  }
  hs0 = h511;
  FLUSH1(0);
#undef LD1
#undef STEP1
#undef FLUSH1
#undef PROC1
}

// ------------- Kernel 2: l0-fwd + l1-fwd fused (8 lanes/batch) --------------
__global__ __launch_bounds__(256, 1) void lstm_fused_fwd(
    const float* __restrict__ x,
    const float* __restrict__ Wih0, const float* __restrict__ Whh0,
    const float* __restrict__ bih0, const float* __restrict__ bhh0,
    const float* __restrict__ Wih1, const float* __restrict__ Whh1,
    const float* __restrict__ bih1, const float* __restrict__ bhh1,
    const float* __restrict__ Wih1r, const float* __restrict__ Whh1r,
    const float* __restrict__ bih1r, const float* __restrict__ bhh1r,
    const float* __restrict__ Wlin, const float* __restrict__ blin,
    const float* __restrict__ y0b,   // [B][64][3][8] shifted
    float* __restrict__ out)         // [B]
{
  int tid = blockIdx.x * 256 + threadIdx.x;
  int b = tid >> 3, lane = tid & 7;
  bool role1 = lane >= 4;               // quad 1 = layer-1 cell
  int j  = role1 ? (lane - 4) : lane;
  int jc = (j < 3) ? j : 2;
  const int r0 = jc, r1 = 3 + jc, r2 = 6 + jc, r3 = 9 + jc;
  const float sI = -LOG2E, sG = -2.f * LOG2E;

  // wif = (i-row, f-row) scaled (sI,sI); wgo = (g-row, o-row) (sG,sI).
  v2f wif0, wif1, wif2, wif3, wif4, wif5, wif6, wif7, wif8;
  v2f wgo0, wgo1, wgo2, wgo3, wgo4, wgo5, wgo6, wgo7, wgo8;
  v2f bif, bgo;
  if (!role1) {
    wif0 = (v2f){Wih0[r0*3+0]*sI, Wih0[r1*3+0]*sI};
    wif1 = (v2f){Wih0[r0*3+1]*sI, Wih0[r1*3+1]*sI};
    wif2 = (v2f){Wih0[r0*3+2]*sI, Wih0[r1*3+2]*sI};
    wif3 = (v2f){0.f, 0.f}; wif4 = (v2f){0.f, 0.f}; wif5 = (v2f){0.f, 0.f};
    wif6 = (v2f){Whh0[r0*3+0]*sI, Whh0[r1*3+0]*sI};
    wif7 = (v2f){Whh0[r0*3+1]*sI, Whh0[r1*3+1]*sI};
    wif8 = (v2f){Whh0[r0*3+2]*sI, Whh0[r1*3+2]*sI};
    wgo0 = (v2f){Wih0[r2*3+0]*sG, Wih0[r3*3+0]*sI};
    wgo1 = (v2f){Wih0[r2*3+1]*sG, Wih0[r3*3+1]*sI};
    wgo2 = (v2f){Wih0[r2*3+2]*sG, Wih0[r3*3+2]*sI};
    wgo3 = (v2f){0.f, 0.f}; wgo4 = (v2f){0.f, 0.f}; wgo5 = (v2f){0.f, 0.f};
    wgo6 = (v2f){Whh0[r2*3+0]*sG, Whh0[r3*3+0]*sI};
    wgo7 = (v2f){Whh0[r2*3+1]*sG, Whh0[r3*3+1]*sI};
    wgo8 = (v2f){Whh0[r2*3+2]*sG, Whh0[r3*3+2]*sI};
    bif = (v2f){(bih0[r0]+bhh0[r0])*sI, (bih0[r1]+bhh0[r1])*sI};
    bgo = (v2f){(bih0[r2]+bhh0[r2])*sG, (bih0[r3]+bhh0[r3])*sI};
  } else {
    wif0 = (v2f){Wih1[r0*6+0]*sI, Wih1[r1*6+0]*sI};
    wif1 = (v2f){Wih1[r0*6+1]*sI, Wih1[r1*6+1]*sI};
    wif2 = (v2f){Wih1[r0*6+2]*sI, Wih1[r1*6+2]*sI};
    wif3 = (v2f){Wih1[r0*6+3]*sI, Wih1[r1*6+3]*sI};
    wif4 = (v2f){Wih1[r0*6+4]*sI, Wih1[r1*6+4]*sI};
    wif5 = (v2f){Wih1[r0*6+5]*sI, Wih1[r1*6+5]*sI};
    wif6 = (v2f){Whh1[r0*3+0]*sI, Whh1[r1*3+0]*sI};
    wif7 = (v2f){Whh1[r0*3+1]*sI, Whh1[r1*3+1]*sI};
    wif8 = (v2f){Whh1[r0*3+2]*sI, Whh1[r1*3+2]*sI};
    wgo0 = (v2f){Wih1[r2*6+0]*sG, Wih1[r3*6+0]*sI};
    wgo1 = (v2f){Wih1[r2*6+1]*sG, Wih1[r3*6+1]*sI};
    wgo2 = (v2f){Wih1[r2*6+2]*sG, Wih1[r3*6+2]*sI};
    wgo3 = (v2f){Wih1[r2*6+3]*sG, Wih1[r3*6+3]*sI};
    wgo4 = (v2f){Wih1[r2*6+4]*sG, Wih1[r3*6+4]*sI};
    wgo5 = (v2f){Wih1[r2*6+5]*sG, Wih1[r3*6+5]*sI};
    wgo6 = (v2f){Whh1[r2*3+0]*sG, Whh1[r3*3+0]*sI};
    wgo7 = (v2f){Whh1[r2*3+1]*sG, Whh1[r3*3+1]*sI};
    wgo8 = (v2f){Whh1[r2*3+2]*sG, Whh1[r3*3+2]*sI};
    bif = (v2f){(bih1[r0]+bhh1[r0])*sI, (bih1[r1]+bhh1[r1])*sI};
    bgo = (v2f){(bih1[r2]+bhh1[r2])*sG, (bih1[r3]+bhh1[r3])*sI};
  }

  float h = 0.f, c = 0.f;
  float ha0 = 0.f, ha1 = 0.f, ha2 = 0.f;  // own cell h(t-1)
  float hb0 = 0.f, hb1 = 0.f, hb2 = 0.f;  // l0 cell h(t-1) (for role1)
  const float4* baseq =
      (const float4*)((role1 ? y0b : x) + (size_t)b * (T_ * 3));

  // y0b block 0 slot 0 = h_bwd(T-1)[j] at j-plane offsets 0,8,16.
  const float* up = y0b + (size_t)b * (T_ * 3);
  float ub0 = up[0], ub1 = up[8], ub2 = up[16];

  float4 p0, p1, p2, p3, p4, p5, q0, q1, q2, q3, q4, q5;

#define LD2(blk, r0_, r1_, r2_, r3_, r4_, r5_) do {                       \
    const float4* _p = baseq + (blk) * 6;                                 \
    r0_ = _p[0]; r1_ = _p[1]; r2_ = _p[2];                                \
    r3_ = _p[3]; r4_ = _p[4]; r5_ = _p[5];                                \
    __builtin_amdgcn_sched_barrier(0); } while (0)

#define GATES2(m0, m1, m2, n0, n1, n2) /* -> cn, hn */                    \
    float v0 = role1 ? hb0 : (m0);                                        \
    float v1 = role1 ? hb1 : (m1);                                        \
    float v2 = role1 ? hb2 : (m2);                                        \
    v2f aif = pkfma(wif0, v0, bif); aif = pkfma(wif1, v1, aif);           \
    aif = pkfma(wif2, v2, aif);                                           \
    v2f nif = wif3 * sp(n0); nif = pkfma(wif4, (n1), nif);                \
    nif = pkfma(wif5, (n2), nif);                                         \
    v2f uif = wif6 * sp(ha0); uif = pkfma(wif7, ha1, uif);                \
    uif = pkfma(wif8, ha2, uif);                                          \
    v2f pif = (aif + nif) + uif;                                          \
    v2f ago = pkfma(wgo0, v0, bgo); ago = pkfma(wgo1, v1, ago);           \
    ago = pkfma(wgo2, v2, ago);                                           \
    v2f ngo = wgo3 * sp(n0); ngo = pkfma(wgo4, (n1), ngo);                \
    ngo = pkfma(wgo5, (n2), ngo);                                         \
    v2f ugo = wgo6 * sp(ha0); ugo = pkfma(wgo7, ha1, ugo);                \
    ugo = pkfma(wgo8, ha2, ugo);                                          \
    v2f pgo = (ago + ngo) + ugo;                                          \
    float ig = act_(pif.x);                                               \
    float fg = act_(pif.y);                                               \
    float gg = __builtin_fmaf(2.f, act_(pgo.x), -1.f);                    \
    float og = act_(pgo.y);                                               \
    float cn = __builtin_fmaf(fg, c, ig * gg);                            \
    float th = __builtin_fmaf(                                            \
        2.f, rcp_(1.f + exp2_(-2.f * LOG2E * cn)), -1.f);                 \
    float hn = og * th;

#define BCAST2() do {                                                     \
    ha0 = dppf<QB0>(h); ha1 = dppf<QB1>(h); ha2 = dppf<QB2>(h);           \
    hb0 = dppf<SHR4>(ha0); hb1 = dppf<SHR4>(ha1); hb2 = dppf<SHR4>(ha2);  \
  } while (0)

#define STEP2(m0, m1, m2, n0, n1, n2) do {                                \
    GATES2(m0, m1, m2, n0, n1, n2)                                        \
    c = cn; h = hn;                                                       \
    BCAST2(); } while (0)

#define STEP2V(m0, m1, m2, n0, n1, n2, VALID) do {                        \
    GATES2(m0, m1, m2, n0, n1, n2)                                        \
    c = (VALID) ? cn : c; h = (VALID) ? hn : h;                           \
    BCAST2(); } while (0)

  // role0 reads its block as [8 s][3 k]; role1 as [3 j][8 s].
#define PROC2(r0_, r1_, r2_, r3_, r4_, r5_) do {                          \
    STEP2(r0_.x, r0_.y, r0_.z,  r0_.x, r2_.x, r4_.x);                     \
    STEP2(r0_.w, r1_.x, r1_.y,  r0_.y, r2_.y, r4_.y);                     \
    STEP2(r1_.z, r1_.w, r2_.x,  r0_.z, r2_.z, r4_.z);                     \
    STEP2(r2_.y, r2_.z, r2_.w,  r0_.w, r2_.w, r4_.w);                     \
    STEP2(r3_.x, r3_.y, r3_.z,  r1_.x, r3_.x, r5_.x);                     \
    STEP2(r3_.w, r4_.x, r4_.y,  r1_.y, r3_.y, r5_.y);                     \
    STEP2(r4_.z, r4_.w, r5_.x,  r1_.z, r3_.z, r5_.z);                     \
    STEP2(r5_.y, r5_.z, r5_.w,  r1_.w, r3_.w, r5_.w); } while (0)

  LD2(0, p0, p1, p2, p3, p4, p5);
  LD2(1, q0, q1, q2, q3, q4, q5);
  // Block 0 peeled: step tt=0 invalid for role1 (it lags one step).
  STEP2V(p0.x, p0.y, p0.z,  p0.x, p2.x, p4.x, !role1);
  STEP2(p0.w, p1.x, p1.y,  p0.y, p2.y, p4.y);
  STEP2(p1.z, p1.w, p2.x,  p0.z, p2.z, p4.z);
  STEP2(p2.y, p2.z, p2.w,  p0.w, p2.w, p4.w);
  STEP2(p3.x, p3.y, p3.z,  p1.x, p3.x, p5.x);
  STEP2(p3.w, p4.x, p4.y,  p1.y, p3.y, p5.y);
  STEP2(p4.z, p4.w, p5.x,  p1.z, p3.z, p5.z);
  STEP2(p5.y, p5.z, p5.w,  p1.w, p3.w, p5.w);
  LD2(2, p0, p1, p2, p3, p4, p5);
  PROC2(q0, q1, q2, q3, q4, q5);
  LD2(3, q0, q1, q2, q3, q4, q5);
  for (int blk = 2; blk < 64; blk += 2) {
    PROC2(p0, p1, p2, p3, p4, p5);
    if (blk + 2 < 64) LD2(blk + 2, p0, p1, p2, p3, p4, p5);
    PROC2(q0, q1, q2, q3, q4, q5);
    if (blk + 3 < 64) LD2(blk + 3, q0, q1, q2, q3, q4, q5);
  }
  // Final step tt=512: role1 processes t=T-1 (inputs hb + ub); role0 frozen.
  STEP2V(ub0, ub1, ub2,  ub0, ub1, ub2, role1);
  // role1 lanes 4-6: h = h1_fwd[j](T-1). ha(role0)/hb(role1) = h0_fwd(T-1).

  float e0 = role1 ? hb0 : ha0;
  float e1 = role1 ? hb1 : ha1;
  float e2 = role1 ? hb2 : ha2;

  // Layer-1 backward: one step from zero state (raw weights, all lanes).
  float h1b;
  {
    float q_i = bih1r[r0] + bhh1r[r0]
              + Wih1r[r0*6+0]*e0 + Wih1r[r0*6+1]*e1 + Wih1r[r0*6+2]*e2
              + Wih1r[r0*6+3]*ub0 + Wih1r[r0*6+4]*ub1 + Wih1r[r0*6+5]*ub2;
    float q_g = bih1r[r2] + bhh1r[r2]
              + Wih1r[r2*6+0]*e0 + Wih1r[r2*6+1]*e1 + Wih1r[r2*6+2]*e2
              + Wih1r[r2*6+3]*ub0 + Wih1r[r2*6+4]*ub1 + Wih1r[r2*6+5]*ub2;
    float q_o = bih1r[r3] + bhh1r[r3]
              + Wih1r[r3*6+0]*e0 + Wih1r[r3*6+1]*e1 + Wih1r[r3*6+2]*e2
              + Wih1r[r3*6+3]*ub0 + Wih1r[r3*6+4]*ub1 + Wih1r[r3*6+5]*ub2;
    float ig = sigm_(q_i), gg = tanh_(q_g), og = sigm_(q_o);
    h1b = og * tanh_(ig * gg);          // c_prev = 0 -> f-gate drops out
  }

  float part = 0.f;
  if (role1) { if (j < 3) part = Wlin[j]     * h;   }
  else       { if (j < 3) part = Wlin[3 + j] * h1b; }
  part += __shfl_xor(part, 1, 8);
  part += __shfl_xor(part, 2, 8);
  part += __shfl_xor(part, 4, 8);
  if (lane == 0) out[b] = sigm_(part + blin[0]);
#undef LD2
#undef GATES2
#undef BCAST2
#undef STEP2
#undef STEP2V
#undef PROC2
}

extern "C" void kernel_launch(void* const* d_in, const int* in_sizes, int n_in,
                              void* d_out, int out_size, void* d_ws, size_t ws_size,
                              hipStream_t stream) {
  const float* x        = (const float*)d_in[0];
  const float* W_ih_l0  = (const float*)d_in[1];
  const float* W_hh_l0  = (const float*)d_in[2];
  const float* b_ih_l0  = (const float*)d_in[3];
  const float* b_hh_l0  = (const float*)d_in[4];
  const float* W_ih_l0r = (const float*)d_in[5];
  const float* W_hh_l0r = (const float*)d_in[6];
  const float* b_ih_l0r = (const float*)d_in[7];
  const float* b_hh_l0r = (const float*)d_in[8];
  const float* W_ih_l1  = (const float*)d_in[9];
  const float* W_hh_l1  = (const float*)d_in[10];
  const float* b_ih_l1  = (const float*)d_in[11];
  const float* b_hh_l1  = (const float*)d_in[12];
  const float* W_ih_l1r = (const float*)d_in[13];
  const float* W_hh_l1r = (const float*)d_in[14];
  const float* b_ih_l1r = (const float*)d_in[15];
  const float* b_hh_l1r = (const float*)d_in[16];
  const float* W_lin    = (const float*)d_in[17];
  const float* b_lin    = (const float*)d_in[18];

  float* y0b = (float*)d_ws;   // [B][64][3][8] fp32 = 48 MB, shifted layout
  float* out = (float*)d_out;

  // K1: 8 lanes/batch -> 65536 threads = 1024 waves (1 wave/SIMD)
  lstm_l0_bwd<<<(B_ * 8) / 256, 256, 0, stream>>>(
      x, W_ih_l0r, W_hh_l0r, b_ih_l0r, b_hh_l0r, y0b);

  // K2: 8 lanes/batch -> 65536 threads = 1024 waves (1 wave/SIMD)
  lstm_fused_fwd<<<(B_ * 8) / 256, 256, 0, stream>>>(
      x, W_ih_l0, W_hh_l0, b_ih_l0, b_hh_l0,
      W_ih_l1, W_hh_l1, b_ih_l1, b_hh_l1,
      W_ih_l1r, W_hh_l1r, b_ih_l1r, b_hh_l1r,
      W_lin, b_lin, y0b, out);
}